// Round 2
// baseline (296.641 us; speedup 1.0000x reference)
//
#include <hip/hip_runtime.h>

#define CH 128
#define CHUNK 4096

typedef float v2f __attribute__((ext_vector_type(2)));
typedef __attribute__((ext_vector_type(8))) short bf16x8;   // 8 bf16 (4 VGPRs)
typedef __attribute__((ext_vector_type(4))) float f32x4;    // MFMA acc

// ---------------------------------------------------------------- fp8 helpers (OCP e4m3)

__device__ __forceinline__ void fp8acc4(unsigned w, float* a) {
  v2f p0 = __builtin_amdgcn_cvt_pk_f32_fp8(w, false);
  v2f p1 = __builtin_amdgcn_cvt_pk_f32_fp8(w, true);
  a[0] += p0.x; a[1] += p0.y; a[2] += p1.x; a[3] += p1.y;
}
__device__ __forceinline__ void fp8acc16(uint4 v, float* a) {
  fp8acc4(v.x, a); fp8acc4(v.y, a + 4); fp8acc4(v.z, a + 8); fp8acc4(v.w, a + 12);
}
__device__ __forceinline__ unsigned fp8pk4(float a, float b, float c, float d) {
  int w = 0;
  w = __builtin_amdgcn_cvt_pk_fp8_f32(a, b, w, false);
  w = __builtin_amdgcn_cvt_pk_fp8_f32(c, d, w, true);
  return (unsigned)w;
}

// ---------------------------------------------------------------- bf16 helpers

__device__ __forceinline__ unsigned bfpack2(float a, float b) {
  unsigned ua = __float_as_uint(a); ua += 0x7FFF + ((ua >> 16) & 1);
  unsigned ub = __float_as_uint(b); ub += 0x7FFF + ((ub >> 16) & 1);
  return (ua >> 16) | (ub & 0xFFFF0000u);
}
__device__ __forceinline__ ushort bf16of(float a) {
  unsigned ua = __float_as_uint(a); ua += 0x7FFF + ((ua >> 16) & 1);
  return (ushort)(ua >> 16);
}
__device__ __forceinline__ uint2 fp8tobf4(unsigned w) {  // 4 fp8 -> 4 bf16
  v2f p0 = __builtin_amdgcn_cvt_pk_f32_fp8(w, false);
  v2f p1 = __builtin_amdgcn_cvt_pk_f32_fp8(w, true);
  return make_uint2(bfpack2(p0.x, p0.y), bfpack2(p1.x, p1.y));
}

// ---------------------------------------------------------------- utilities

__device__ __forceinline__ int edge_at(const void* ei, long long i, int is64) {
  if (is64) return (int)((const long long*)ei)[i];
  return ((const int*)ei)[i];
}

// In-kernel dtype detect: high words of the first 64 int64 entries are all 0
// iff input is int64.
__device__ __forceinline__ int detect64(const void* ei) {
  int lane = threadIdx.x & 63;
  int v = ((const int*)ei)[2 * lane + 1];
  return (__ballot(v != 0) == 0ULL) ? 1 : 0;
}

// parallel prep: block 0 zeros counters + partials; blocks 1..16 transform
// weights.
__global__ __launch_bounds__(256) void k_prep(const float* __restrict__ W1,
                                              const float* __restrict__ b1,
                                              const float* __restrict__ W2,
                                              const float* __restrict__ b2,
                                              ushort* __restrict__ Wt1,
                                              ushort* __restrict__ Wt2,
                                              float* __restrict__ b1p,
                                              float* __restrict__ b2p,
                                              int* bcnt, int* rcnt,
                                              float* part) {
  int t = threadIdx.x, b = blockIdx.x;
  if (b == 0) {
    for (int i = t; i < 256 * 16; i += 256) { bcnt[i] = 0; rcnt[i] = 0; }
    for (int i = t; i < 64 * CH; i += 256) part[i] = 0.f;
    return;
  }
  int base = (b - 1) * 1024;
#pragma unroll
  for (int k = 0; k < 4; ++k) {
    int i = base + k * 256 + t;
    int n = i >> 7, kk = i & 127;
    Wt1[i] = bf16of(W1[(size_t)kk * CH + n]);
    int ko = (kk & 7) * 16 + (kk >> 3);
    Wt2[i] = bf16of(W2[(size_t)ko * CH + n]);
  }
  if (b == 1 && t < CH) b1p[t] = b1[(t & 7) * 16 + (t >> 3)];
  if (b == 2 && t < CH) b2p[t] = b2[(t & 7) * 16 + (t >> 3)];
}

// P1: per-bucket edge counts for BOTH c-buckets and r-buckets
__global__ __launch_bounds__(256) void kb_count(const void* ei,
                                                int* bcnt, int* rcnt, int E, int N) {
  __shared__ int hist[256], rhist[256];
  int t = threadIdx.x;
  int f = detect64(ei);
  hist[t] = 0; rhist[t] = 0;
  __syncthreads();
  for (int e = blockIdx.x * 256 + t; e < E; e += gridDim.x * 256) {
    int r = edge_at(ei, e, f);
    int c = edge_at(ei, (long long)E + e, f);
    if ((unsigned)r < (unsigned)N && (unsigned)c < (unsigned)N) {
      atomicAdd(&hist[c >> 8], 1);
      atomicAdd(&rhist[r >> 8], 1);
    }
  }
  __syncthreads();
  if (hist[t] > 0) atomicAdd(&bcnt[t * 16], hist[t]);
  if (rhist[t] > 0) atomicAdd(&rcnt[t * 16], rhist[t]);
}

// P2: scan both bucket-count arrays -> bases + cursors; rowptr[N]=total
__global__ void kb_scan(const int* bcnt, int* bbase, int* gcursor,
                        const int* rcnt, int* rbase, int* rcursor,
                        int* rowptr, int NB, int N) {
  __shared__ int tmp[256];
  int t = threadIdx.x;
  int v = (t < NB) ? bcnt[t * 16] : 0;
  tmp[t] = v;
  __syncthreads();
  for (int off = 1; off < 256; off <<= 1) {
    int u = (t >= off) ? tmp[t - off] : 0;
    __syncthreads();
    tmp[t] += u;
    __syncthreads();
  }
  bbase[t] = tmp[t] - v;
  gcursor[t * 16] = tmp[t] - v;
  if (t == 255) rowptr[N] = tmp[255];
  __syncthreads();
  int rv = (t < NB) ? rcnt[t * 16] : 0;
  tmp[t] = rv;
  __syncthreads();
  for (int off = 1; off < 256; off <<= 1) {
    int u = (t >= off) ? tmp[t - off] : 0;
    __syncthreads();
    tmp[t] += u;
    __syncthreads();
  }
  rbase[t] = tmp[t] - rv;
  rcursor[t * 16] = tmp[t] - rv;
}

// P3: merged dual bucket-sort, DIRECT global run writes.
// Records: cpk = r|((c&255)<<24), rpk mirrored.
__global__ __launch_bounds__(256) void kb_scatter2(const void* ei,
                                                   int* gcur, int* rcur,
                                                   unsigned* __restrict__ cpk,
                                                   unsigned* __restrict__ rpk,
                                                   int E, int N) {
  __shared__ int hist[256], lcur[256], gbl[256];
  int t = threadIdx.x;
  int e0 = blockIdx.x * CHUNK;
  int f = detect64(ei);
  int rr[16], cc[16];
#pragma unroll
  for (int k = 0; k < 16; ++k) {
    int e = e0 + k * 256 + t;
    rr[k] = 0; cc[k] = -1;
    if (e < E) {
      int r = edge_at(ei, e, f);
      int c = edge_at(ei, (long long)E + e, f);
      if ((unsigned)r < (unsigned)N && (unsigned)c < (unsigned)N) { rr[k] = r; cc[k] = c; }
    }
  }
  // ---- pass 1: key = c
  hist[t] = 0;
  __syncthreads();
#pragma unroll
  for (int k = 0; k < 16; ++k)
    if (cc[k] >= 0) atomicAdd(&hist[cc[k] >> 8], 1);
  __syncthreads();
  if (hist[t] > 0) gbl[t] = atomicAdd(&gcur[t * 16], hist[t]);
  lcur[t] = 0;
  __syncthreads();
#pragma unroll
  for (int k = 0; k < 16; ++k) {
    if (cc[k] >= 0) {
      int b = cc[k] >> 8;
      int pos = atomicAdd(&lcur[b], 1);
      cpk[gbl[b] + pos] = (unsigned)rr[k] | ((unsigned)(cc[k] & 255) << 24);
    }
  }
  __syncthreads();
  // ---- pass 2: key = r
  hist[t] = 0;
  __syncthreads();
#pragma unroll
  for (int k = 0; k < 16; ++k)
    if (cc[k] >= 0) atomicAdd(&hist[rr[k] >> 8], 1);
  __syncthreads();
  if (hist[t] > 0) gbl[t] = atomicAdd(&rcur[t * 16], hist[t]);
  lcur[t] = 0;
  __syncthreads();
#pragma unroll
  for (int k = 0; k < 16; ++k) {
    if (cc[k] >= 0) {
      int b = rr[k] >> 8;
      int pos = atomicAdd(&lcur[b], 1);
      rpk[gbl[b] + pos] = (unsigned)cc[k] | ((unsigned)(rr[k] & 255) << 24);
    }
  }
}

// P4: per-bucket CSR build + dinv from packed c-sorted records.
__global__ __launch_bounds__(1024) void kb_csr(const unsigned* __restrict__ cpk,
                                               const int* __restrict__ bcnt,
                                               const int* __restrict__ bbase,
                                               int* rowptr, int* src,
                                               float* dinv, int N) {
  __shared__ int hist[256], lcur[256], tmp[256];
  int t = threadIdx.x;
  int b = blockIdx.x;
  int node0 = b << 8;
  int nn = min(256, N - node0);
  int base = bbase[b];
  int cnt = bcnt[b * 16];
  if (t < 256) hist[t] = 0;
  __syncthreads();
  for (int j = t; j < cnt; j += 1024)
    atomicAdd(&hist[cpk[base + j] >> 24], 1);
  __syncthreads();
  if (t < 256) tmp[t] = hist[t];
  __syncthreads();
  for (int off = 1; off < 256; off <<= 1) {
    int u = (t < 256 && t >= off) ? tmp[t - off] : 0;
    __syncthreads();
    if (t < 256) tmp[t] += u;
    __syncthreads();
  }
  if (t < 256) {
    int v = hist[t];
    lcur[t] = tmp[t] - v;
    if (t < nn) {
      rowptr[node0 + t] = base + tmp[t] - v;
      dinv[node0 + t] = rsqrtf((float)(v + 1));  // +1 self-loop
    }
  }
  __syncthreads();
  for (int j = t; j < cnt; j += 1024) {
    unsigned w = cpk[base + j];
    int pos = atomicAdd(&lcur[w >> 24], 1);
    src[base + pos] = (int)(w & 0xFFFFFF);
  }
}

// P5: wp from packed r-sorted records — LDS atomics only
__global__ __launch_bounds__(1024) void kb_wp(const unsigned* __restrict__ rpk,
                                              const int* __restrict__ rcnt,
                                              const int* __restrict__ rbase,
                                              const float* __restrict__ dinv,
                                              float* __restrict__ wp, int N) {
  __shared__ float wpl[256];
  int t = threadIdx.x;
  int b = blockIdx.x;
  int node0 = b << 8;
  int nn = min(256, N - node0);
  int base = rbase[b];
  int cnt = rcnt[b * 16];
  if (t < 256) wpl[t] = 0.f;
  __syncthreads();
  for (int j = t; j < cnt; j += 1024) {
    unsigned w = rpk[base + j];
    atomicAdd(&wpl[w >> 24], dinv[w & 0xFFFFFF]);
  }
  __syncthreads();
  if (t < nn) wp[node0 + t] = wpl[t];
}

// ---------------------------------------------------------------- MFMA GEMM
// Output split into two 64B fp8 planes (ch_new 0..63 / 64..127) for L2-resident aggs.
template <int FP8A>
__global__ __launch_bounds__(256) void k_gemm_m(const void* __restrict__ Alo,
                                                const void* __restrict__ Ahi,
                                                const ushort* __restrict__ Wt,
                                                const float* __restrict__ dinv,
                                                uint2* __restrict__ Clo,
                                                uint2* __restrict__ Chi, int N) {
  __shared__ __align__(16) ushort As[64 * 136];
  __shared__ __align__(16) ushort Bs[128 * 136];
  int t = threadIdx.x;
  int row0 = blockIdx.x * 64;

  if (FP8A == 0) {
    const float4* A = (const float4*)Alo;  // [N][32]
    int k4 = t & 31, m0 = t >> 5;
    for (int mm = m0; mm < 64; mm += 8) {
      int gr = row0 + mm;
      float4 v = make_float4(0.f, 0.f, 0.f, 0.f);
      if (gr < N) v = A[(size_t)gr * 32 + k4];
      *(uint2*)&As[mm * 136 + k4 * 4] = make_uint2(bfpack2(v.x, v.y), bfpack2(v.z, v.w));
    }
  } else {
    const uint4* A0 = (const uint4*)Alo;  // [N][4] lo plane
    const uint4* A1 = (const uint4*)Ahi;  // [N][4] hi plane
    int k8 = t & 7, m0 = t >> 3;
    for (int mm = m0; mm < 64; mm += 32) {
      int gr = row0 + mm;
      uint4 v = make_uint4(0, 0, 0, 0);
      if (gr < N) v = (k8 < 4) ? A0[(size_t)gr * 4 + k8] : A1[(size_t)gr * 4 + k8 - 4];
      ushort* d = &As[mm * 136 + k8 * 16];
      *(uint2*)&d[0]  = fp8tobf4(v.x);
      *(uint2*)&d[4]  = fp8tobf4(v.y);
      *(uint2*)&d[8]  = fp8tobf4(v.z);
      *(uint2*)&d[12] = fp8tobf4(v.w);
    }
  }
  {
    const uint4* W4 = (const uint4*)Wt;
    int rw = t >> 1, half = t & 1;
#pragma unroll
    for (int i = 0; i < 8; ++i) {
      uint4 v = W4[rw * 16 + half * 8 + i];
      *(uint4*)&Bs[rw * 136 + half * 64 + i * 8] = v;
    }
  }
  __syncthreads();

  int lane = t & 63, w = t >> 6;
  int m = lane & 15, quad = lane >> 4;
  f32x4 acc[8] = {};
#pragma unroll
  for (int kb = 0; kb < 128; kb += 32) {
    bf16x8 af = *(const bf16x8*)&As[(w * 16 + m) * 136 + kb + quad * 8];
#pragma unroll
    for (int nt = 0; nt < 8; ++nt) {
      bf16x8 bfv = *(const bf16x8*)&Bs[(nt * 16 + m) * 136 + kb + quad * 8];
      acc[nt] = __builtin_amdgcn_mfma_f32_16x16x32_bf16(af, bfv, acc[nt], 0, 0, 0);
    }
  }
  uint2* pl = (m < 8) ? Clo : Chi;
#pragma unroll
  for (int reg = 0; reg < 4; ++reg) {
    int gr = row0 + w * 16 + quad * 4 + reg;
    if (gr < N) {
      float s = dinv[gr];
      unsigned w0 = fp8pk4(acc[0][reg] * s, acc[1][reg] * s, acc[2][reg] * s, acc[3][reg] * s);
      unsigned w1 = fp8pk4(acc[4][reg] * s, acc[5][reg] * s, acc[6][reg] * s, acc[7][reg] * s);
      pl[(size_t)gr * 8 + (m & 7)] = make_uint2(w0, w1);
    }
  }
}

// ---------------------------------------------------------------- aggregate (fp8, per-plane)
// blockIdx.y selects the plane. Request-count optimized: src indices loaded as
// int4 (2 loads / 8 edges) instead of 8 scalar loads — index reads were half
// of all memory-pipe requests (same line dup'd over the 4 tx lanes). A short
// scalar head aligns j to 4 so the int4 loads are 16B-aligned.
// FINAL=1: layer-2+3 collapse fused in.
template <int FINAL>
__global__ __launch_bounds__(256) void k_agg2(const uint4* __restrict__ hlo,
                                              const uint4* __restrict__ hhi,
                                              const float* __restrict__ dinv,
                                              const float* __restrict__ wp,
                                              const int* __restrict__ rowptr,
                                              const int* __restrict__ src,
                                              const float* __restrict__ biasH,
                                              uint4* __restrict__ outlo,
                                              uint4* __restrict__ outhi,
                                              float* __restrict__ part, int N) {
  int tx = threadIdx.x;  // 0..3 : 16-channel chunk
  int ty = threadIdx.y;  // 0..63: node slot
  int pl = blockIdx.y;
  const uint4* hh = pl ? hhi : hlo;
  uint4* outp = pl ? outhi : outlo;
  float bv[16];
#pragma unroll
  for (int i = 0; i < 16; ++i) bv[i] = biasH[pl * 64 + tx * 16 + i];
  float wacc[16];
  if (FINAL) {
#pragma unroll
    for (int i = 0; i < 16; ++i) wacc[i] = 0.f;
  }

  for (int c = blockIdx.x * 64 + ty; c < N; c += gridDim.x * 64) {
    float acc[16] = {};
    fp8acc16(hh[(size_t)c * 4 + tx], acc);  // self-loop
    int j = rowptr[c], je = rowptr[c + 1];
    // scalar head: align j to 4 (src base is 512B-aligned)
    for (; j < je && (j & 3); ++j) fp8acc16(hh[(size_t)src[j] * 4 + tx], acc);
    for (; j + 8 <= je; j += 8) {
      int4 s0 = *(const int4*)(src + j);
      int4 s1 = *(const int4*)(src + j + 4);
      uint4 v0 = hh[(size_t)s0.x * 4 + tx];
      uint4 v1 = hh[(size_t)s0.y * 4 + tx];
      uint4 v2 = hh[(size_t)s0.z * 4 + tx];
      uint4 v3 = hh[(size_t)s0.w * 4 + tx];
      uint4 v4 = hh[(size_t)s1.x * 4 + tx];
      uint4 v5 = hh[(size_t)s1.y * 4 + tx];
      uint4 v6 = hh[(size_t)s1.z * 4 + tx];
      uint4 v7 = hh[(size_t)s1.w * 4 + tx];
      fp8acc16(v0, acc); fp8acc16(v1, acc); fp8acc16(v2, acc); fp8acc16(v3, acc);
      fp8acc16(v4, acc); fp8acc16(v5, acc); fp8acc16(v6, acc); fp8acc16(v7, acc);
    }
    if (j + 4 <= je) {
      int4 s0 = *(const int4*)(src + j);
      uint4 v0 = hh[(size_t)s0.x * 4 + tx];
      uint4 v1 = hh[(size_t)s0.y * 4 + tx];
      uint4 v2 = hh[(size_t)s0.z * 4 + tx];
      uint4 v3 = hh[(size_t)s0.w * 4 + tx];
      fp8acc16(v0, acc); fp8acc16(v1, acc); fp8acc16(v2, acc); fp8acc16(v3, acc);
      j += 4;
    }
    for (; j < je; ++j) fp8acc16(hh[(size_t)src[j] * 4 + tx], acc);
    float s = dinv[c];
    float o[16];
#pragma unroll
    for (int i = 0; i < 16; ++i) o[i] = fmaxf(acc[i] * s + bv[i], 0.f);
    if (FINAL) {
      float wt = (s + wp[c]) * s;
#pragma unroll
      for (int i = 0; i < 16; ++i) wacc[i] += wt * o[i];
    } else {
      uint4 ov;
      ov.x = fp8pk4(o[0], o[1], o[2], o[3]);
      ov.y = fp8pk4(o[4], o[5], o[6], o[7]);
      ov.z = fp8pk4(o[8], o[9], o[10], o[11]);
      ov.w = fp8pk4(o[12], o[13], o[14], o[15]);
      outp[(size_t)c * 4 + tx] = ov;
    }
  }

  if constexpr (FINAL != 0) {
    __shared__ float red[64][64];
#pragma unroll
    for (int i = 0; i < 16; ++i) red[ty][tx * 16 + i] = wacc[i];
    __syncthreads();
    for (int sft = 32; sft > 0; sft >>= 1) {
      if (ty < sft) {
#pragma unroll
        for (int i = 0; i < 16; ++i) red[ty][tx * 16 + i] += red[ty + sft][tx * 16 + i];
      }
      __syncthreads();
    }
    if (ty == 0) {
      float* slot = &part[(size_t)(blockIdx.x & 63) * CH + pl * 64 + tx * 16];
#pragma unroll
      for (int i = 0; i < 16; ++i) atomicAdd(&slot[i], red[0][tx * 16 + i]);
    }
  }
}

// ---------------------------------------------------------------- epilogue (1024 thr)
__global__ __launch_bounds__(1024) void k_final(const float* __restrict__ partial,
                                                const float* __restrict__ W3,
                                                const float* __restrict__ b3,
                                                const float* __restrict__ Wl,
                                                const float* __restrict__ bl,
                                                float* __restrict__ out, float invN) {
  __shared__ float us[CH];
  __shared__ float red[8][CH];
  int t = threadIdx.x;
  int ch = t & 127, g = t >> 7;
  float s = 0.f;
#pragma unroll
  for (int b = 0; b < 8; ++b)
    s += partial[(size_t)(g * 8 + b) * CH + ch];
  red[g][ch] = s;
  __syncthreads();
  if (g == 0) {
    float u = 0.f;
#pragma unroll
    for (int k = 1; k < 8; ++k) u += red[k][ch];
    us[ch] = (s + u) * invN;
  }
  __syncthreads();
  float p = 0.f;
#pragma unroll
  for (int k = 0; k < 16; ++k) {
    int kk = g * 16 + k;
    int ko = (kk & 7) * 16 + (kk >> 3);  // un-permute channel
    p += us[kk] * W3[(size_t)ko * CH + ch];
  }
  red[g][ch] = p;
  __syncthreads();
  if (g == 0) {
    float S = red[0][ch];
#pragma unroll
    for (int k = 1; k < 8; ++k) S += red[k][ch];
    us[ch] = (S + b3[ch]) * Wl[ch];
  }
  __syncthreads();
  for (int off = 64; off > 0; off >>= 1) {
    if (t < off) us[t] += us[t + off];
    __syncthreads();
  }
  if (t == 0) out[0] = 1.f / (1.f + expf(-(us[0] + bl[0])));
}

// ---------------------------------------------------------------- launch

extern "C" void kernel_launch(void* const* d_in, const int* in_sizes, int n_in,
                              void* d_out, int out_size, void* d_ws, size_t ws_size,
                              hipStream_t stream) {
  const float* x  = (const float*)d_in[0];
  const void*  ei = d_in[1];
  const float* W1 = (const float*)d_in[3];
  const float* b1 = (const float*)d_in[4];
  const float* W2 = (const float*)d_in[5];
  const float* b2 = (const float*)d_in[6];
  const float* W3 = (const float*)d_in[7];
  const float* b3 = (const float*)d_in[8];
  const float* Wl = (const float*)d_in[9];
  const float* bl = (const float*)d_in[10];
  float* out = (float*)d_out;

  const int N = in_sizes[0] / CH;
  const int E = in_sizes[1] / 2;
  const int NB = (N + 255) >> 8;

  char* ws = (char*)d_ws;
  size_t off = 0;
  auto alloc = [&](size_t bytes) -> void* {
    void* p = ws + off;
    off += (bytes + 511) & ~(size_t)511;
    return p;
  };
  float*    dinv   = (float*)alloc((size_t)N * 4);
  float*    wp     = (float*)alloc((size_t)N * 4);
  int*      rowptr = (int*)alloc((size_t)(N + 1) * 4);
  int*      bcnt   = (int*)alloc(256 * 16 * 4);
  int*      bbase  = (int*)alloc(256 * 4);
  int*      gcur   = (int*)alloc(256 * 16 * 4);
  int*      rcnt   = (int*)alloc(256 * 16 * 4);
  int*      rbase  = (int*)alloc(256 * 4);
  int*      rcur   = (int*)alloc(256 * 16 * 4);
  float*    part   = (float*)alloc((size_t)64 * CH * 4);
  ushort*   Wt1    = (ushort*)alloc(128 * 128 * 2);
  ushort*   Wt2    = (ushort*)alloc(128 * 128 * 2);
  float*    b1p    = (float*)alloc(CH * 4);
  float*    b2p    = (float*)alloc(CH * 4);
  int*      src    = (int*)alloc((size_t)E * 4);
  unsigned* cpk    = (unsigned*)alloc((size_t)E * 4);
  unsigned* rpk    = (unsigned*)alloc((size_t)E * 4);
  uint4*    hlo    = (uint4*)alloc((size_t)N * 64);  // fp8 plane ch 0..63
  uint4*    hhi    = (uint4*)alloc((size_t)N * 64);
  uint4*    xlo    = (uint4*)alloc((size_t)N * 64);
  uint4*    xhi    = (uint4*)alloc((size_t)N * 64);

  const int nCk = (E + CHUNK - 1) / CHUNK;

  // ---- preprocessing
  k_prep<<<17, 256, 0, stream>>>(W1, b1, W2, b2, Wt1, Wt2, b1p, b2p, bcnt, rcnt, part);
  kb_count<<<nCk, 256, 0, stream>>>(ei, bcnt, rcnt, E, N);
  kb_scan<<<1, 256, 0, stream>>>(bcnt, bbase, gcur, rcnt, rbase, rcur, rowptr, NB, N);
  kb_scatter2<<<nCk, 256, 0, stream>>>(ei, gcur, rcur, cpk, rpk, E, N);
  kb_csr<<<NB, 1024, 0, stream>>>(cpk, bcnt, bbase, rowptr, src, dinv, N);
  kb_wp<<<NB, 1024, 0, stream>>>(rpk, rcnt, rbase, dinv, wp, N);

  // ---- layers 1 & 2 (MFMA GEMMs + plane-merged gather-aggregates)
  const int gblocks = (N + 63) / 64;
  const int pgx = (N + 63) / 64;
  dim3 pblk(4, 64);

  k_gemm_m<0><<<gblocks, 256, 0, stream>>>(x, nullptr, Wt1, dinv, (uint2*)hlo, (uint2*)hhi, N);
  k_agg2<0><<<dim3(pgx, 2), pblk, 0, stream>>>(hlo, hhi, dinv, nullptr, rowptr, src, b1p,
                                               xlo, xhi, nullptr, N);
  k_gemm_m<1><<<gblocks, 256, 0, stream>>>(xlo, xhi, Wt2, dinv, (uint2*)hlo, (uint2*)hhi, N);
  // ---- layer-2 aggregate with layer-3 collapse fused (no x2 round-trip)
  k_agg2<1><<<dim3(pgx, 2), pblk, 0, stream>>>(hlo, hhi, dinv, wp, rowptr, src, b2p,
                                               nullptr, nullptr, part, N);
  k_final<<<1, 1024, 0, stream>>>(part, W3, b3, Wl, bl, out, 1.0f / (float)N);
}

// Round 3
// 286.128 us; speedup vs baseline: 1.0367x; 1.0367x over previous
//
#include <hip/hip_runtime.h>

#define CH 128
#define CHUNK 4096

typedef float v2f __attribute__((ext_vector_type(2)));
typedef __attribute__((ext_vector_type(8))) short bf16x8;   // 8 bf16 (4 VGPRs)
typedef __attribute__((ext_vector_type(4))) float f32x4;    // MFMA acc

// ---------------------------------------------------------------- fp8 helpers (OCP e4m3)

__device__ __forceinline__ void fp8acc4(unsigned w, float* a) {
  v2f p0 = __builtin_amdgcn_cvt_pk_f32_fp8(w, false);
  v2f p1 = __builtin_amdgcn_cvt_pk_f32_fp8(w, true);
  a[0] += p0.x; a[1] += p0.y; a[2] += p1.x; a[3] += p1.y;
}
__device__ __forceinline__ void fp8acc16(uint4 v, float* a) {
  fp8acc4(v.x, a); fp8acc4(v.y, a + 4); fp8acc4(v.z, a + 8); fp8acc4(v.w, a + 12);
}
__device__ __forceinline__ unsigned fp8pk4(float a, float b, float c, float d) {
  int w = 0;
  w = __builtin_amdgcn_cvt_pk_fp8_f32(a, b, w, false);
  w = __builtin_amdgcn_cvt_pk_fp8_f32(c, d, w, true);
  return (unsigned)w;
}

// ---------------------------------------------------------------- bf16 helpers

__device__ __forceinline__ unsigned bfpack2(float a, float b) {
  unsigned ua = __float_as_uint(a); ua += 0x7FFF + ((ua >> 16) & 1);
  unsigned ub = __float_as_uint(b); ub += 0x7FFF + ((ub >> 16) & 1);
  return (ua >> 16) | (ub & 0xFFFF0000u);
}
__device__ __forceinline__ ushort bf16of(float a) {
  unsigned ua = __float_as_uint(a); ua += 0x7FFF + ((ua >> 16) & 1);
  return (ushort)(ua >> 16);
}
__device__ __forceinline__ uint2 fp8tobf4(unsigned w) {  // 4 fp8 -> 4 bf16
  v2f p0 = __builtin_amdgcn_cvt_pk_f32_fp8(w, false);
  v2f p1 = __builtin_amdgcn_cvt_pk_f32_fp8(w, true);
  return make_uint2(bfpack2(p0.x, p0.y), bfpack2(p1.x, p1.y));
}

// ---------------------------------------------------------------- utilities

__device__ __forceinline__ int edge_at(const void* ei, long long i, int is64) {
  if (is64) return (int)((const long long*)ei)[i];
  return ((const int*)ei)[i];
}

// In-kernel dtype detect: high words of the first 64 int64 entries are all 0
// iff input is int64.
__device__ __forceinline__ int detect64(const void* ei) {
  int lane = threadIdx.x & 63;
  int v = ((const int*)ei)[2 * lane + 1];
  return (__ballot(v != 0) == 0ULL) ? 1 : 0;
}

// parallel prep: block 0 zeros counters + partials; blocks 1..16 transform
// weights.
__global__ __launch_bounds__(256) void k_prep(const float* __restrict__ W1,
                                              const float* __restrict__ b1,
                                              const float* __restrict__ W2,
                                              const float* __restrict__ b2,
                                              ushort* __restrict__ Wt1,
                                              ushort* __restrict__ Wt2,
                                              float* __restrict__ b1p,
                                              float* __restrict__ b2p,
                                              int* bcnt, int* rcnt,
                                              float* part) {
  int t = threadIdx.x, b = blockIdx.x;
  if (b == 0) {
    for (int i = t; i < 256 * 16; i += 256) { bcnt[i] = 0; rcnt[i] = 0; }
    for (int i = t; i < 64 * CH; i += 256) part[i] = 0.f;
    return;
  }
  int base = (b - 1) * 1024;
#pragma unroll
  for (int k = 0; k < 4; ++k) {
    int i = base + k * 256 + t;
    int n = i >> 7, kk = i & 127;
    Wt1[i] = bf16of(W1[(size_t)kk * CH + n]);
    int ko = (kk & 7) * 16 + (kk >> 3);
    Wt2[i] = bf16of(W2[(size_t)ko * CH + n]);
  }
  if (b == 1 && t < CH) b1p[t] = b1[(t & 7) * 16 + (t >> 3)];
  if (b == 2 && t < CH) b2p[t] = b2[(t & 7) * 16 + (t >> 3)];
}

// P1: per-bucket edge counts for BOTH c-buckets and r-buckets
__global__ __launch_bounds__(256) void kb_count(const void* ei,
                                                int* bcnt, int* rcnt, int E, int N) {
  __shared__ int hist[256], rhist[256];
  int t = threadIdx.x;
  int f = detect64(ei);
  hist[t] = 0; rhist[t] = 0;
  __syncthreads();
  for (int e = blockIdx.x * 256 + t; e < E; e += gridDim.x * 256) {
    int r = edge_at(ei, e, f);
    int c = edge_at(ei, (long long)E + e, f);
    if ((unsigned)r < (unsigned)N && (unsigned)c < (unsigned)N) {
      atomicAdd(&hist[c >> 8], 1);
      atomicAdd(&rhist[r >> 8], 1);
    }
  }
  __syncthreads();
  if (hist[t] > 0) atomicAdd(&bcnt[t * 16], hist[t]);
  if (rhist[t] > 0) atomicAdd(&rcnt[t * 16], rhist[t]);
}

// P2: scan both bucket-count arrays -> bases + cursors; rowptr[N]=total
__global__ void kb_scan(const int* bcnt, int* bbase, int* gcursor,
                        const int* rcnt, int* rbase, int* rcursor,
                        int* rowptr, int NB, int N) {
  __shared__ int tmp[256];
  int t = threadIdx.x;
  int v = (t < NB) ? bcnt[t * 16] : 0;
  tmp[t] = v;
  __syncthreads();
  for (int off = 1; off < 256; off <<= 1) {
    int u = (t >= off) ? tmp[t - off] : 0;
    __syncthreads();
    tmp[t] += u;
    __syncthreads();
  }
  bbase[t] = tmp[t] - v;
  gcursor[t * 16] = tmp[t] - v;
  if (t == 255) rowptr[N] = tmp[255];
  __syncthreads();
  int rv = (t < NB) ? rcnt[t * 16] : 0;
  tmp[t] = rv;
  __syncthreads();
  for (int off = 1; off < 256; off <<= 1) {
    int u = (t >= off) ? tmp[t - off] : 0;
    __syncthreads();
    tmp[t] += u;
    __syncthreads();
  }
  rbase[t] = tmp[t] - rv;
  rcursor[t * 16] = tmp[t] - rv;
}

// P3: merged dual bucket-sort, DIRECT global run writes.
// Records: cpk = r|((c&255)<<24), rpk mirrored.
__global__ __launch_bounds__(256) void kb_scatter2(const void* ei,
                                                   int* gcur, int* rcur,
                                                   unsigned* __restrict__ cpk,
                                                   unsigned* __restrict__ rpk,
                                                   int E, int N) {
  __shared__ int hist[256], lcur[256], gbl[256];
  int t = threadIdx.x;
  int e0 = blockIdx.x * CHUNK;
  int f = detect64(ei);
  int rr[16], cc[16];
#pragma unroll
  for (int k = 0; k < 16; ++k) {
    int e = e0 + k * 256 + t;
    rr[k] = 0; cc[k] = -1;
    if (e < E) {
      int r = edge_at(ei, e, f);
      int c = edge_at(ei, (long long)E + e, f);
      if ((unsigned)r < (unsigned)N && (unsigned)c < (unsigned)N) { rr[k] = r; cc[k] = c; }
    }
  }
  // ---- pass 1: key = c
  hist[t] = 0;
  __syncthreads();
#pragma unroll
  for (int k = 0; k < 16; ++k)
    if (cc[k] >= 0) atomicAdd(&hist[cc[k] >> 8], 1);
  __syncthreads();
  if (hist[t] > 0) gbl[t] = atomicAdd(&gcur[t * 16], hist[t]);
  lcur[t] = 0;
  __syncthreads();
#pragma unroll
  for (int k = 0; k < 16; ++k) {
    if (cc[k] >= 0) {
      int b = cc[k] >> 8;
      int pos = atomicAdd(&lcur[b], 1);
      cpk[gbl[b] + pos] = (unsigned)rr[k] | ((unsigned)(cc[k] & 255) << 24);
    }
  }
  __syncthreads();
  // ---- pass 2: key = r
  hist[t] = 0;
  __syncthreads();
#pragma unroll
  for (int k = 0; k < 16; ++k)
    if (cc[k] >= 0) atomicAdd(&hist[rr[k] >> 8], 1);
  __syncthreads();
  if (hist[t] > 0) gbl[t] = atomicAdd(&rcur[t * 16], hist[t]);
  lcur[t] = 0;
  __syncthreads();
#pragma unroll
  for (int k = 0; k < 16; ++k) {
    if (cc[k] >= 0) {
      int b = rr[k] >> 8;
      int pos = atomicAdd(&lcur[b], 1);
      rpk[gbl[b] + pos] = (unsigned)cc[k] | ((unsigned)(rr[k] & 255) << 24);
    }
  }
}

// P4: per-bucket CSR build + dinv from packed c-sorted records.
__global__ __launch_bounds__(1024) void kb_csr(const unsigned* __restrict__ cpk,
                                               const int* __restrict__ bcnt,
                                               const int* __restrict__ bbase,
                                               int* rowptr, int* src,
                                               float* dinv, int N) {
  __shared__ int hist[256], lcur[256], tmp[256];
  int t = threadIdx.x;
  int b = blockIdx.x;
  int node0 = b << 8;
  int nn = min(256, N - node0);
  int base = bbase[b];
  int cnt = bcnt[b * 16];
  if (t < 256) hist[t] = 0;
  __syncthreads();
  for (int j = t; j < cnt; j += 1024)
    atomicAdd(&hist[cpk[base + j] >> 24], 1);
  __syncthreads();
  if (t < 256) tmp[t] = hist[t];
  __syncthreads();
  for (int off = 1; off < 256; off <<= 1) {
    int u = (t < 256 && t >= off) ? tmp[t - off] : 0;
    __syncthreads();
    if (t < 256) tmp[t] += u;
    __syncthreads();
  }
  if (t < 256) {
    int v = hist[t];
    lcur[t] = tmp[t] - v;
    if (t < nn) {
      rowptr[node0 + t] = base + tmp[t] - v;
      dinv[node0 + t] = rsqrtf((float)(v + 1));  // +1 self-loop
    }
  }
  __syncthreads();
  for (int j = t; j < cnt; j += 1024) {
    unsigned w = cpk[base + j];
    int pos = atomicAdd(&lcur[w >> 24], 1);
    src[base + pos] = (int)(w & 0xFFFFFF);
  }
}

// P5: wp from packed r-sorted records — LDS atomics only
__global__ __launch_bounds__(1024) void kb_wp(const unsigned* __restrict__ rpk,
                                              const int* __restrict__ rcnt,
                                              const int* __restrict__ rbase,
                                              const float* __restrict__ dinv,
                                              float* __restrict__ wp, int N) {
  __shared__ float wpl[256];
  int t = threadIdx.x;
  int b = blockIdx.x;
  int node0 = b << 8;
  int nn = min(256, N - node0);
  int base = rbase[b];
  int cnt = rcnt[b * 16];
  if (t < 256) wpl[t] = 0.f;
  __syncthreads();
  for (int j = t; j < cnt; j += 1024) {
    unsigned w = rpk[base + j];
    atomicAdd(&wpl[w >> 24], dinv[w & 0xFFFFFF]);
  }
  __syncthreads();
  if (t < nn) wp[node0 + t] = wpl[t];
}

// ---------------------------------------------------------------- MFMA GEMM
// Output: single fp8 row of 128B per node ([N][16] uint2) — full-L2-line rows
// for the aggregate's gathers.
template <int FP8A>
__global__ __launch_bounds__(256) void k_gemm_m(const void* __restrict__ Ain,
                                                const ushort* __restrict__ Wt,
                                                const float* __restrict__ dinv,
                                                uint2* __restrict__ Cb, int N) {
  __shared__ __align__(16) ushort As[64 * 136];
  __shared__ __align__(16) ushort Bs[128 * 136];
  int t = threadIdx.x;
  int row0 = blockIdx.x * 64;

  if (FP8A == 0) {
    const float4* A = (const float4*)Ain;  // [N][32]
    int k4 = t & 31, m0 = t >> 5;
    for (int mm = m0; mm < 64; mm += 8) {
      int gr = row0 + mm;
      float4 v = make_float4(0.f, 0.f, 0.f, 0.f);
      if (gr < N) v = A[(size_t)gr * 32 + k4];
      *(uint2*)&As[mm * 136 + k4 * 4] = make_uint2(bfpack2(v.x, v.y), bfpack2(v.z, v.w));
    }
  } else {
    const uint4* A = (const uint4*)Ain;  // [N][8] fp8 128B rows
    int k8 = t & 7, m0 = t >> 3;
    for (int mm = m0; mm < 64; mm += 32) {
      int gr = row0 + mm;
      uint4 v = make_uint4(0, 0, 0, 0);
      if (gr < N) v = A[(size_t)gr * 8 + k8];
      ushort* d = &As[mm * 136 + k8 * 16];
      *(uint2*)&d[0]  = fp8tobf4(v.x);
      *(uint2*)&d[4]  = fp8tobf4(v.y);
      *(uint2*)&d[8]  = fp8tobf4(v.z);
      *(uint2*)&d[12] = fp8tobf4(v.w);
    }
  }
  {
    const uint4* W4 = (const uint4*)Wt;
    int rw = t >> 1, half = t & 1;
#pragma unroll
    for (int i = 0; i < 8; ++i) {
      uint4 v = W4[rw * 16 + half * 8 + i];
      *(uint4*)&Bs[rw * 136 + half * 64 + i * 8] = v;
    }
  }
  __syncthreads();

  int lane = t & 63, w = t >> 6;
  int m = lane & 15, quad = lane >> 4;
  f32x4 acc[8] = {};
#pragma unroll
  for (int kb = 0; kb < 128; kb += 32) {
    bf16x8 af = *(const bf16x8*)&As[(w * 16 + m) * 136 + kb + quad * 8];
#pragma unroll
    for (int nt = 0; nt < 8; ++nt) {
      bf16x8 bfv = *(const bf16x8*)&Bs[(nt * 16 + m) * 136 + kb + quad * 8];
      acc[nt] = __builtin_amdgcn_mfma_f32_16x16x32_bf16(af, bfv, acc[nt], 0, 0, 0);
    }
  }
#pragma unroll
  for (int reg = 0; reg < 4; ++reg) {
    int gr = row0 + w * 16 + quad * 4 + reg;
    if (gr < N) {
      float s = dinv[gr];
      unsigned w0 = fp8pk4(acc[0][reg] * s, acc[1][reg] * s, acc[2][reg] * s, acc[3][reg] * s);
      unsigned w1 = fp8pk4(acc[4][reg] * s, acc[5][reg] * s, acc[6][reg] * s, acc[7][reg] * s);
      Cb[(size_t)gr * 16 + m] = make_uint2(w0, w1);
    }
  }
}

// ---------------------------------------------------------------- aggregate (fp8, 128B rows)
// Merged planes: one gather per edge = one full 128B L2 line (8 lanes x 16B).
// 16-edge unroll -> 16 uint4 gathers in flight per thread (2x the old MLP).
// block (8,32): tx = 16-channel chunk, ty = node slot.
// FINAL=1: layer-2+3 collapse fused; shfl-based block reduce (no LDS conflicts).
template <int FINAL>
__global__ __launch_bounds__(256) void k_agg2(const uint4* __restrict__ hb,
                                              const float* __restrict__ dinv,
                                              const float* __restrict__ wp,
                                              const int* __restrict__ rowptr,
                                              const int* __restrict__ src,
                                              const float* __restrict__ biasH,
                                              uint4* __restrict__ xb,
                                              float* __restrict__ part, int N) {
  int tx = threadIdx.x;  // 0..7 : 16-channel chunk
  int ty = threadIdx.y;  // 0..31: node slot
  float bv[16];
#pragma unroll
  for (int i = 0; i < 16; ++i) bv[i] = biasH[tx * 16 + i];
  float wacc[16];
  if constexpr (FINAL != 0) {
#pragma unroll
    for (int i = 0; i < 16; ++i) wacc[i] = 0.f;
  }

  for (int c = blockIdx.x * 32 + ty; c < N; c += gridDim.x * 32) {
    float acc[16] = {};
    fp8acc16(hb[(size_t)c * 8 + tx], acc);  // self-loop
    int j = rowptr[c], je = rowptr[c + 1];
    // scalar head: align j to 4 (src base is 512B-aligned)
    for (; j < je && (j & 3); ++j) fp8acc16(hb[(size_t)src[j] * 8 + tx], acc);
    for (; j + 16 <= je; j += 16) {
      int4 s0 = *(const int4*)(src + j);
      int4 s1 = *(const int4*)(src + j + 4);
      int4 s2 = *(const int4*)(src + j + 8);
      int4 s3 = *(const int4*)(src + j + 12);
      uint4 v0 = hb[(size_t)s0.x * 8 + tx];
      uint4 v1 = hb[(size_t)s0.y * 8 + tx];
      uint4 v2 = hb[(size_t)s0.z * 8 + tx];
      uint4 v3 = hb[(size_t)s0.w * 8 + tx];
      uint4 v4 = hb[(size_t)s1.x * 8 + tx];
      uint4 v5 = hb[(size_t)s1.y * 8 + tx];
      uint4 v6 = hb[(size_t)s1.z * 8 + tx];
      uint4 v7 = hb[(size_t)s1.w * 8 + tx];
      uint4 v8 = hb[(size_t)s2.x * 8 + tx];
      uint4 v9 = hb[(size_t)s2.y * 8 + tx];
      uint4 va = hb[(size_t)s2.z * 8 + tx];
      uint4 vb = hb[(size_t)s2.w * 8 + tx];
      uint4 vc = hb[(size_t)s3.x * 8 + tx];
      uint4 vd = hb[(size_t)s3.y * 8 + tx];
      uint4 ve = hb[(size_t)s3.z * 8 + tx];
      uint4 vf = hb[(size_t)s3.w * 8 + tx];
      fp8acc16(v0, acc); fp8acc16(v1, acc); fp8acc16(v2, acc); fp8acc16(v3, acc);
      fp8acc16(v4, acc); fp8acc16(v5, acc); fp8acc16(v6, acc); fp8acc16(v7, acc);
      fp8acc16(v8, acc); fp8acc16(v9, acc); fp8acc16(va, acc); fp8acc16(vb, acc);
      fp8acc16(vc, acc); fp8acc16(vd, acc); fp8acc16(ve, acc); fp8acc16(vf, acc);
    }
    if (j + 8 <= je) {
      int4 s0 = *(const int4*)(src + j);
      int4 s1 = *(const int4*)(src + j + 4);
      uint4 v0 = hb[(size_t)s0.x * 8 + tx];
      uint4 v1 = hb[(size_t)s0.y * 8 + tx];
      uint4 v2 = hb[(size_t)s0.z * 8 + tx];
      uint4 v3 = hb[(size_t)s0.w * 8 + tx];
      uint4 v4 = hb[(size_t)s1.x * 8 + tx];
      uint4 v5 = hb[(size_t)s1.y * 8 + tx];
      uint4 v6 = hb[(size_t)s1.z * 8 + tx];
      uint4 v7 = hb[(size_t)s1.w * 8 + tx];
      fp8acc16(v0, acc); fp8acc16(v1, acc); fp8acc16(v2, acc); fp8acc16(v3, acc);
      fp8acc16(v4, acc); fp8acc16(v5, acc); fp8acc16(v6, acc); fp8acc16(v7, acc);
      j += 8;
    }
    if (j + 4 <= je) {
      int4 s0 = *(const int4*)(src + j);
      uint4 v0 = hb[(size_t)s0.x * 8 + tx];
      uint4 v1 = hb[(size_t)s0.y * 8 + tx];
      uint4 v2 = hb[(size_t)s0.z * 8 + tx];
      uint4 v3 = hb[(size_t)s0.w * 8 + tx];
      fp8acc16(v0, acc); fp8acc16(v1, acc); fp8acc16(v2, acc); fp8acc16(v3, acc);
      j += 4;
    }
    for (; j < je; ++j) fp8acc16(hb[(size_t)src[j] * 8 + tx], acc);
    float s = dinv[c];
    float o[16];
#pragma unroll
    for (int i = 0; i < 16; ++i) o[i] = fmaxf(acc[i] * s + bv[i], 0.f);
    if constexpr (FINAL != 0) {
      float wt = (s + wp[c]) * s;
#pragma unroll
      for (int i = 0; i < 16; ++i) wacc[i] += wt * o[i];
    } else {
      uint4 ov;
      ov.x = fp8pk4(o[0], o[1], o[2], o[3]);
      ov.y = fp8pk4(o[4], o[5], o[6], o[7]);
      ov.z = fp8pk4(o[8], o[9], o[10], o[11]);
      ov.w = fp8pk4(o[12], o[13], o[14], o[15]);
      xb[(size_t)c * 8 + tx] = ov;
    }
  }

  if constexpr (FINAL != 0) {
    // wave reduce across ty (lane = ty*8 + tx, tx preserved mod 8)
#pragma unroll
    for (int i = 0; i < 16; ++i) {
      wacc[i] += __shfl_down(wacc[i], 32);
      wacc[i] += __shfl_down(wacc[i], 16);
      wacc[i] += __shfl_down(wacc[i], 8);
    }
    __shared__ float redw[4][8][16];
    int wv = ty >> 3;
    if ((ty & 7) == 0) {
#pragma unroll
      for (int i = 0; i < 16; ++i) redw[wv][tx][i] = wacc[i];
    }
    __syncthreads();
    int t = ty * 8 + tx;
    if (t < 128) {
      int cx = t >> 4, i = t & 15;
      float sum = redw[0][cx][i] + redw[1][cx][i] + redw[2][cx][i] + redw[3][cx][i];
      atomicAdd(&part[(size_t)(blockIdx.x & 63) * CH + cx * 16 + i], sum);
    }
  }
}

// ---------------------------------------------------------------- epilogue (1024 thr)
__global__ __launch_bounds__(1024) void k_final(const float* __restrict__ partial,
                                                const float* __restrict__ W3,
                                                const float* __restrict__ b3,
                                                const float* __restrict__ Wl,
                                                const float* __restrict__ bl,
                                                float* __restrict__ out, float invN) {
  __shared__ float us[CH];
  __shared__ float red[8][CH];
  int t = threadIdx.x;
  int ch = t & 127, g = t >> 7;
  float s = 0.f;
#pragma unroll
  for (int b = 0; b < 8; ++b)
    s += partial[(size_t)(g * 8 + b) * CH + ch];
  red[g][ch] = s;
  __syncthreads();
  if (g == 0) {
    float u = 0.f;
#pragma unroll
    for (int k = 1; k < 8; ++k) u += red[k][ch];
    us[ch] = (s + u) * invN;
  }
  __syncthreads();
  float p = 0.f;
#pragma unroll
  for (int k = 0; k < 16; ++k) {
    int kk = g * 16 + k;
    int ko = (kk & 7) * 16 + (kk >> 3);  // un-permute channel
    p += us[kk] * W3[(size_t)ko * CH + ch];
  }
  red[g][ch] = p;
  __syncthreads();
  if (g == 0) {
    float S = red[0][ch];
#pragma unroll
    for (int k = 1; k < 8; ++k) S += red[k][ch];
    us[ch] = (S + b3[ch]) * Wl[ch];
  }
  __syncthreads();
  for (int off = 64; off > 0; off >>= 1) {
    if (t < off) us[t] += us[t + off];
    __syncthreads();
  }
  if (t == 0) out[0] = 1.f / (1.f + expf(-(us[0] + bl[0])));
}

// ---------------------------------------------------------------- launch

extern "C" void kernel_launch(void* const* d_in, const int* in_sizes, int n_in,
                              void* d_out, int out_size, void* d_ws, size_t ws_size,
                              hipStream_t stream) {
  const float* x  = (const float*)d_in[0];
  const void*  ei = d_in[1];
  const float* W1 = (const float*)d_in[3];
  const float* b1 = (const float*)d_in[4];
  const float* W2 = (const float*)d_in[5];
  const float* b2 = (const float*)d_in[6];
  const float* W3 = (const float*)d_in[7];
  const float* b3 = (const float*)d_in[8];
  const float* Wl = (const float*)d_in[9];
  const float* bl = (const float*)d_in[10];
  float* out = (float*)d_out;

  const int N = in_sizes[0] / CH;
  const int E = in_sizes[1] / 2;
  const int NB = (N + 255) >> 8;

  char* ws = (char*)d_ws;
  size_t off = 0;
  auto alloc = [&](size_t bytes) -> void* {
    void* p = ws + off;
    off += (bytes + 511) & ~(size_t)511;
    return p;
  };
  float*    dinv   = (float*)alloc((size_t)N * 4);
  float*    wp     = (float*)alloc((size_t)N * 4);
  int*      rowptr = (int*)alloc((size_t)(N + 1) * 4);
  int*      bcnt   = (int*)alloc(256 * 16 * 4);
  int*      bbase  = (int*)alloc(256 * 4);
  int*      gcur   = (int*)alloc(256 * 16 * 4);
  int*      rcnt   = (int*)alloc(256 * 16 * 4);
  int*      rbase  = (int*)alloc(256 * 4);
  int*      rcur   = (int*)alloc(256 * 16 * 4);
  float*    part   = (float*)alloc((size_t)64 * CH * 4);
  ushort*   Wt1    = (ushort*)alloc(128 * 128 * 2);
  ushort*   Wt2    = (ushort*)alloc(128 * 128 * 2);
  float*    b1p    = (float*)alloc(CH * 4);
  float*    b2p    = (float*)alloc(CH * 4);
  int*      src    = (int*)alloc((size_t)E * 4);
  unsigned* cpk    = (unsigned*)alloc((size_t)E * 4);
  unsigned* rpk    = (unsigned*)alloc((size_t)E * 4);
  uint4*    hb     = (uint4*)alloc((size_t)N * 128);  // fp8 128B rows
  uint4*    xb     = (uint4*)alloc((size_t)N * 128);

  const int nCk = (E + CHUNK - 1) / CHUNK;

  // ---- preprocessing
  k_prep<<<17, 256, 0, stream>>>(W1, b1, W2, b2, Wt1, Wt2, b1p, b2p, bcnt, rcnt, part);
  kb_count<<<nCk, 256, 0, stream>>>(ei, bcnt, rcnt, E, N);
  kb_scan<<<1, 256, 0, stream>>>(bcnt, bbase, gcur, rcnt, rbase, rcur, rowptr, NB, N);
  kb_scatter2<<<nCk, 256, 0, stream>>>(ei, gcur, rcur, cpk, rpk, E, N);
  kb_csr<<<NB, 1024, 0, stream>>>(cpk, bcnt, bbase, rowptr, src, dinv, N);
  kb_wp<<<NB, 1024, 0, stream>>>(rpk, rcnt, rbase, dinv, wp, N);

  // ---- layers 1 & 2 (MFMA GEMMs + merged-row gather-aggregates)
  const int gblocks = (N + 63) / 64;
  const int pgx = (N + 31) / 32;
  dim3 pblk(8, 32);

  k_gemm_m<0><<<gblocks, 256, 0, stream>>>(x, Wt1, dinv, (uint2*)hb, N);
  k_agg2<0><<<pgx, pblk, 0, stream>>>(hb, dinv, nullptr, rowptr, src, b1p, xb, nullptr, N);
  k_gemm_m<1><<<gblocks, 256, 0, stream>>>(xb, Wt2, dinv, (uint2*)hb, N);
  // ---- layer-2 aggregate with layer-3 collapse fused
  k_agg2<1><<<pgx, pblk, 0, stream>>>(hb, dinv, wp, rowptr, src, b2p, nullptr, part, N);
  k_final<<<1, 1024, 0, stream>>>(part, W3, b3, Wl, bl, out, 1.0f / (float)N);
}